// Round 5
// baseline (266.305 us; speedup 1.0000x reference)
//
#include <hip/hip_runtime.h>
#include <math.h>

typedef _Float16 h8 __attribute__((ext_vector_type(8)));
typedef _Float16 h4 __attribute__((ext_vector_type(4)));
typedef float    f4 __attribute__((ext_vector_type(4)));

#define SAMPLES 64
#define HIDDEN  256

// d_ws layout (units: _Float16). Weights pre-split hi/lo, fragment order
// (identical map for A- and B-operand use):
//   ws[((kg*CT + ct)*64 + ln)*8 + j] = W[kg*32 + ((ln>>4)<<3) + j][ct*16 + (ln&15)]
#define OFF_W0HI 0            // [2][16][64][8]  = 16384 halfs
#define OFF_W0LO 16384
#define OFF_W1HI 32768        // [8][16][64][8]  = 65536
#define OFF_W1LO 98304
#define OFF_W2HI 163840
#define OFF_W2LO 229376
#define OFF_W3HI 294912       // [8][64][8] = 4096 (W3 cols padded 4->16)
#define OFF_W3LO 299008

// 26 blocks: 0..1 W0(kg), 2..9 W1, 10..17 W2, 18..25 W3. LDS-staged so both
// global loads and global stores are coalesced.
__global__ void prep_weights(const float* __restrict__ W0,
                             const float* __restrict__ W1,
                             const float* __restrict__ W2,
                             const float* __restrict__ W3,
                             _Float16* __restrict__ ws)
{
    __shared__ float tile[32][257];
    const int tid = threadIdx.x;
    const int bid = blockIdx.x;

    const float* src; int hioff, looff, kg, kmax, wide;
    if (bid < 2)       { src=W0; hioff=OFF_W0HI; looff=OFF_W0LO; kg=bid;    kmax=63;  wide=1; }
    else if (bid < 10) { src=W1; hioff=OFF_W1HI; looff=OFF_W1LO; kg=bid-2;  kmax=256; wide=1; }
    else if (bid < 18) { src=W2; hioff=OFF_W2HI; looff=OFF_W2LO; kg=bid-10; kmax=256; wide=1; }
    else               { src=W3; hioff=OFF_W3HI; looff=OFF_W3LO; kg=bid-18; kmax=256; wide=0; }

    if (wide) {
        // stage rows kg*32..+31, cols 0..255 (coalesced)
        for (int r = 0; r < 32; ++r) {
            int k = kg*32 + r;
            tile[r][tid] = (k < kmax) ? src[k*256 + tid] : 0.0f;
        }
        __syncthreads();
#pragma unroll
        for (int t = 0; t < 4; ++t) {
            int b  = tid + t*256;          // 0..1023 = [ct][ln]
            int ct = b >> 6, ln = b & 63;
            int col = ct*16 + (ln & 15);
            int kl  = (ln >> 4) << 3;
            h8 vh, vl;
#pragma unroll
            for (int j = 0; j < 8; ++j) {
                float v = tile[kl + j][col];
                _Float16 h = (_Float16)v;
                vh[j] = h;
                vl[j] = (_Float16)(v - (float)h);
            }
            int di = ((kg*16 + ct)*64 + ln);
            ((h8*)(ws + hioff))[di] = vh;  // consecutive ln -> coalesced 16B
            ((h8*)(ws + looff))[di] = vl;
        }
    } else {
        if (tid < 128) {
            int r = tid >> 2, c = tid & 3;
            tile[r][c] = src[(kg*32 + r)*4 + c];
        }
        __syncthreads();
        if (tid < 64) {
            int ln = tid;
            int col = ln & 15;
            int kl  = (ln >> 4) << 3;
            h8 vh, vl;
#pragma unroll
            for (int j = 0; j < 8; ++j) {
                float v = (col < 4) ? tile[kl + j][col] : 0.0f;
                _Float16 h = (_Float16)v;
                vh[j] = h;
                vl[j] = (_Float16)(v - (float)h);
            }
            int di = kg*64 + ln;
            ((h8*)(ws + hioff))[di] = vh;
            ((h8*)(ws + looff))[di] = vl;
        }
    }
}

__device__ __forceinline__ f4 mfma3(h8 ahi, h8 alo, h8 bhi, h8 blo, f4 c)
{
    c = __builtin_amdgcn_mfma_f32_16x16x32_f16(alo, bhi, c, 0, 0, 0);
    c = __builtin_amdgcn_mfma_f32_16x16x32_f16(ahi, blo, c, 0, 0, 0);
    c = __builtin_amdgcn_mfma_f32_16x16x32_f16(ahi, bhi, c, 0, 0, 0);
    return c;
}

// Swapped orientation: D[ch][samp] = W^T @ H^T. Wave (csl,sh) does
// channels csl*64..+63 x samples sh*32..+31. Writeback: relu + hi/lo split
// into next layer's B-frag layout, one ds_write_b64 per tile per array.
template<int NKG>
__device__ __forceinline__ void dense_layer(const _Float16* __restrict__ Whi,
                                            const _Float16* __restrict__ Wlo,
                                            const float*    __restrict__ bias,
                                            _Float16* Bhi, _Float16* Blo,
                                            int csl, int sh, int lane)
{
    const int q  = lane >> 4;
    const int jl = lane & 15;
    f4 acc[4][2];
#pragma unroll
    for (int cht = 0; cht < 4; ++cht) {
        f4 bb = ((const f4*)(bias + csl*64 + cht*16))[q];   // acc row r -> ch q*4+r
        acc[cht][0] = bb;
        acc[cht][1] = bb;
    }
    const h8* wh  = (const h8*)Whi;
    const h8* wl  = (const h8*)Wlo;
    const h8* bhp = (const h8*)Bhi;
    const h8* blp = (const h8*)Blo;

    for (int kg = 0; kg < NKG; ++kg) {
        h8 bh[2], bl[2];
#pragma unroll
        for (int s2 = 0; s2 < 2; ++s2) {
            int bi = (kg*4 + sh*2 + s2)*64 + lane;      // ds_read_b128, conflict-free
            bh[s2] = bhp[bi];
            bl[s2] = blp[bi];
        }
#pragma unroll
        for (int cht = 0; cht < 4; ++cht) {
            int wi = (kg*16 + csl*4 + cht)*64 + lane;   // coalesced 16 B/lane, L2-hot
            h8 ah = wh[wi];
            h8 al = wl[wi];
            acc[cht][0] = mfma3(ah, al, bh[0], bl[0], acc[cht][0]);
            acc[cht][1] = mfma3(ah, al, bh[1], bl[1], acc[cht][1]);
        }
    }

    __syncthreads();   // all waves done reading before in-place overwrite

#pragma unroll
    for (int cht = 0; cht < 4; ++cht) {
        // ch = csl*64 + cht*16 + q*4 + r  -> next-layer k
        int kgp = csl*2 + (cht >> 1);
        int lnp = jl + 16*(2*(cht & 1) + (q >> 1));
        int jb  = 4*(q & 1);
#pragma unroll
        for (int s2 = 0; s2 < 2; ++s2) {
            int st = sh*2 + s2;
            h4 vh, vl;
#pragma unroll
            for (int r = 0; r < 4; ++r) {
                float v = fmaxf(acc[cht][s2][r], 0.0f);
                _Float16 hh = (_Float16)v;
                vh[r] = hh;
                vl[r] = (_Float16)(v - (float)hh);
            }
            int base = ((kgp*4 + st)*64 + lnp)*8 + jb;
            *(h4*)(Bhi + base) = vh;
            *(h4*)(Blo + base) = vl;
        }
    }
    __syncthreads();
}

// NOTE: second launch_bounds arg behaves as MIN BLOCKS PER CU on hipcc
// (r4 evidence: (512,4) -> 64-VGPR cap -> spill). (512,2) -> 128-VGPR cap,
// matching the 2-blocks/CU the 64 KB LDS allows.
__launch_bounds__(512, 2)
__global__ void nerf_fused(const float* __restrict__ origins,
                           const float* __restrict__ dirs,
                           const float* __restrict__ nearp,
                           const float* __restrict__ farp,
                           const float* __restrict__ b0,
                           const float* __restrict__ b1,
                           const float* __restrict__ b2,
                           const float* __restrict__ b3,
                           const _Float16* __restrict__ ws,
                           float* __restrict__ out)
{
    extern __shared__ _Float16 sm[];
    _Float16* Bhi = sm;            // [kg][4st][64ln][8] = 16384 halfs = 32 KB
    _Float16* Blo = sm + 16384;    // 32 KB (total 64 KB -> 2 blocks/CU, 16 waves)

    const int tid  = threadIdx.x;
    const int wv   = tid >> 6;
    const int lane = tid & 63;
    const int csl  = wv >> 1;      // channel slice 0..3
    const int sh   = wv & 1;       // sample half 0..1
    const int ray  = blockIdx.x;

    const float near = nearp[0];
    const float far  = farp[0];
    const float step = (far - near) * (1.0f / 64.0f);

    const float ox = origins[ray*3+0], oy = origins[ray*3+1], oz = origins[ray*3+2];
    const float dx = dirs[ray*3+0],    dy = dirs[ray*3+1],    dz = dirs[ray*3+2];

    // ---- PE directly into B-frag layout (K padded 63->64): one h8 per thread
    {
        int b  = tid;                    // = (kg*4+st)*64 + ln
        int ln = b & 63;
        int sample = ((b >> 6) & 3)*16 + (ln & 15);
        int k0 = (b >> 8)*32 + ((ln >> 4) << 3);
        float mid = (near + (float)sample*step) + (near + (float)(sample+1)*step)*0.5f;
        float c3[3] = { ox + mid*dx, oy + mid*dy, oz + mid*dz };
        h8 vh, vl;
#pragma unroll
        for (int j = 0; j < 8; ++j) {
            int k = k0 + j;
            float v;
            if (k < 3) v = c3[k];
            else if (k < 63) {
                int t = k - 3, l = t/6, r = t%6, d = r%3;
                float a = c3[d] * (float)(1 << l);
                v = (r < 3) ? sinf(a) : cosf(a);
            } else v = 0.0f;
            _Float16 hh = (_Float16)v;
            vh[j] = hh;
            vl[j] = (_Float16)(v - (float)hh);
        }
        ((h8*)Bhi)[b] = vh;
        ((h8*)Blo)[b] = vl;
    }
    __syncthreads();

    dense_layer<2>(ws+OFF_W0HI, ws+OFF_W0LO, b0, Bhi, Blo, csl, sh, lane);
    dense_layer<8>(ws+OFF_W1HI, ws+OFF_W1LO, b1, Bhi, Blo, csl, sh, lane);
    dense_layer<8>(ws+OFF_W2HI, ws+OFF_W2LO, b2, Bhi, Blo, csl, sh, lane);

    // ---- head: D[16pad ch][64 samp], K split across 8 waves (kg = wv)
    f4 hacc[4];
#pragma unroll
    for (int st = 0; st < 4; ++st) hacc[st] = (f4){0.f, 0.f, 0.f, 0.f};
    {
        h8 ah = ((const h8*)(ws+OFF_W3HI))[wv*64 + lane];
        h8 al = ((const h8*)(ws+OFF_W3LO))[wv*64 + lane];
        const h8* bhp = (const h8*)Bhi;
        const h8* blp = (const h8*)Blo;
#pragma unroll
        for (int st = 0; st < 4; ++st) {
            int bi = (wv*4 + st)*64 + lane;
            hacc[st] = mfma3(ah, al, bhp[bi], blp[bi], hacc[st]);
        }
    }
    __syncthreads();                       // B reads done -> safe to alias

    f4* part = (f4*)sm;                    // [wv][st][lane] f4 = 32 KB (Bhi region)
#pragma unroll
    for (int st = 0; st < 4; ++st) part[(wv*4 + st)*64 + lane] = hacc[st];
    __syncthreads();

    float* headv = (float*)(sm + 16384);   // [64 samp][4] f32 = 1 KB (Blo region)
    if (tid < 256) {
        int st = tid >> 6, l = tid & 63;
        f4 s = part[(0*4 + st)*64 + l];
#pragma unroll
        for (int w = 1; w < 8; ++w) s += part[(w*4 + st)*64 + l];
        int q = l >> 4, jl = l & 15;
        if (q == 0) {                      // rows 0..3 = the real 4 channels
            s += *(const f4*)b3;
            ((f4*)headv)[st*16 + jl] = s;  // [sample] -> (r,g,b,sigma)
        }
    }
    __syncthreads();

    // ---- compositing: wave 0, lane = sample
    if (tid < 64) {
        f4 f = ((const f4*)headv)[tid];
        const int p = tid;
        float sigma = fmaxf(f[3], 0.0f);
        float delta = (near + (float)(p + 1)*step) - (near + (float)p*step);
        float alpha = 1.0f - expf(-sigma * delta);
        float om    = 1.0f - alpha;

        float prod = om;
#pragma unroll
        for (int off = 1; off < 64; off <<= 1) {
            float v = __shfl_up(prod, off, 64);
            if (p >= off) prod *= v;
        }
        float T = __shfl_up(prod, 1, 64);
        if (p == 0) T = 1.0f;
        float w = T * alpha;

        float r  = w * (1.0f / (1.0f + expf(-f[0])));
        float g  = w * (1.0f / (1.0f + expf(-f[1])));
        float bb = w * (1.0f / (1.0f + expf(-f[2])));
#pragma unroll
        for (int off = 32; off > 0; off >>= 1) {
            r  += __shfl_down(r,  off, 64);
            g  += __shfl_down(g,  off, 64);
            bb += __shfl_down(bb, off, 64);
        }
        if (p == 0) {
            out[ray*3 + 0] = r;
            out[ray*3 + 1] = g;
            out[ray*3 + 2] = bb;
        }
    }
}

extern "C" void kernel_launch(void* const* d_in, const int* in_sizes, int n_in,
                              void* d_out, int out_size, void* d_ws, size_t ws_size,
                              hipStream_t stream) {
    const float* origins = (const float*)d_in[0];
    const float* dirs    = (const float*)d_in[1];
    const float* nearp   = (const float*)d_in[2];
    const float* farp    = (const float*)d_in[3];
    const float* W0      = (const float*)d_in[4];
    const float* b0      = (const float*)d_in[5];
    const float* W1      = (const float*)d_in[6];
    const float* b1      = (const float*)d_in[7];
    const float* W2      = (const float*)d_in[8];
    const float* b2      = (const float*)d_in[9];
    const float* W3      = (const float*)d_in[10];
    const float* b3      = (const float*)d_in[11];
    float* out           = (float*)d_out;
    _Float16* ws         = (_Float16*)d_ws;

    const int nrays = in_sizes[0] / 3;

    prep_weights<<<dim3(26), dim3(256), 0, stream>>>(W0, W1, W2, W3, ws);

    const size_t shmem = 32768 * sizeof(_Float16);   // 64 KiB
    hipFuncSetAttribute(reinterpret_cast<const void*>(nerf_fused),
                        hipFuncAttributeMaxDynamicSharedMemorySize,
                        (int)shmem);
    nerf_fused<<<dim3(nrays), dim3(512), shmem, stream>>>(
        origins, dirs, nearp, farp, b0, b1, b2, b3, ws, out);
}

// Round 6
// 173.603 us; speedup vs baseline: 1.5340x; 1.5340x over previous
//
#include <hip/hip_runtime.h>
#include <math.h>

typedef _Float16 h8 __attribute__((ext_vector_type(8)));
typedef _Float16 h4 __attribute__((ext_vector_type(4)));
typedef float    f4 __attribute__((ext_vector_type(4)));

#define SAMPLES 64
#define HIDDEN  256

// d_ws layout (units: _Float16). Weights pre-split hi/lo, fragment order:
//   ws[((kg*16 + ct)*64 + ln)*8 + j] = W[kg*32 + ((ln>>4)<<3) + j][ct*16 + (ln&15)]
#define OFF_W0HI 0            // [2][16][64][8]  = 16384 halfs
#define OFF_W0LO 16384
#define OFF_W1HI 32768        // [8][16][64][8]  = 65536
#define OFF_W1LO 98304
#define OFF_W2HI 163840
#define OFF_W2LO 229376
#define OFF_W3HI 294912       // [8][64][8] = 4096 (W3 cols padded 4->16)
#define OFF_W3LO 299008

// One fragment tile per wave: 296 waves over 74 blocks. Loads hit L2 in
// 64B segments; stores are fully coalesced 16B/lane.
__launch_bounds__(256)
__global__ void prep_weights(const float* __restrict__ W0,
                             const float* __restrict__ W1,
                             const float* __restrict__ W2,
                             const float* __restrict__ W3,
                             _Float16* __restrict__ ws)
{
    const int ln = threadIdx.x & 63;
    const int t  = blockIdx.x * 4 + (threadIdx.x >> 6);   // tile id 0..295
    if (t >= 296) return;

    const float* src; int hioff, looff, kg, ct, kmax, colmax, wide;
    if (t < 32)       { src=W0; hioff=OFF_W0HI; looff=OFF_W0LO; kg=t>>4;        ct=t&15;        kmax=63;  colmax=256; wide=1; }
    else if (t < 160) { int u=t-32;  src=W1; hioff=OFF_W1HI; looff=OFF_W1LO; kg=u>>4; ct=u&15; kmax=256; colmax=256; wide=1; }
    else if (t < 288) { int u=t-160; src=W2; hioff=OFF_W2HI; looff=OFF_W2LO; kg=u>>4; ct=u&15; kmax=256; colmax=256; wide=1; }
    else              { int u=t-288; src=W3; hioff=OFF_W3HI; looff=OFF_W3LO; kg=u;    ct=0;    kmax=256; colmax=4;   wide=0; }

    const int col = ct*16 + (ln & 15);
    const int k0  = kg*32 + ((ln >> 4) << 3);
    h8 vh, vl;
#pragma unroll
    for (int j = 0; j < 8; ++j) {
        int k = k0 + j;
        float v = (k < kmax && col < colmax) ? src[k*colmax + col] : 0.0f;
        _Float16 h = (_Float16)v;
        vh[j] = h;
        vl[j] = (_Float16)(v - (float)h);
    }
    int di = wide ? ((kg*16 + ct)*64 + ln) : (kg*64 + ln);
    ((h8*)(ws + hioff))[di] = vh;
    ((h8*)(ws + looff))[di] = vl;
}

__device__ __forceinline__ f4 mfma3(h8 ahi, h8 alo, h8 bhi, h8 blo, f4 c)
{
    c = __builtin_amdgcn_mfma_f32_16x16x32_f16(alo, bhi, c, 0, 0, 0);
    c = __builtin_amdgcn_mfma_f32_16x16x32_f16(ahi, blo, c, 0, 0, 0);
    c = __builtin_amdgcn_mfma_f32_16x16x32_f16(ahi, bhi, c, 0, 0, 0);
    return c;
}

// Swapped orientation: D[ch][samp] = W^T @ H^T. Wave wv owns channels
// wv*32..+31 (cht=0,1) x ALL 64 samples (st=0..3): 4 global h8 loads/kg
// (explicitly prefetched one kg ahead), 8 ds_read_b128/kg, 24 MFMA/kg.
template<int NKG>
__device__ __forceinline__ void dense_layer(const _Float16* __restrict__ Whi,
                                            const _Float16* __restrict__ Wlo,
                                            const float*    __restrict__ bias,
                                            _Float16* Bhi, _Float16* Blo,
                                            int wv, int lane)
{
    const int q  = lane >> 4;
    const int jl = lane & 15;
    f4 acc[2][4];
#pragma unroll
    for (int cht = 0; cht < 2; ++cht) {
        f4 bb = ((const f4*)bias)[wv*8 + cht*4 + q];   // acc row r -> ch q*4+r
#pragma unroll
        for (int st = 0; st < 4; ++st) acc[cht][st] = bb;
    }
    const h8* wh  = (const h8*)Whi;
    const h8* wl  = (const h8*)Wlo;
    const h8* bhp = (const h8*)Bhi;
    const h8* blp = (const h8*)Blo;

    h8 cah[2], cal[2];
#pragma unroll
    for (int cht = 0; cht < 2; ++cht) {            // kg=0 prefetch
        int wi = (wv*2 + cht)*64 + lane;
        cah[cht] = wh[wi];
        cal[cht] = wl[wi];
    }

#pragma unroll
    for (int kg = 0; kg < NKG; ++kg) {
        h8 nah[2], nal[2];
        int kn = (kg + 1 < NKG) ? kg + 1 : kg;     // harmless re-load on last iter
#pragma unroll
        for (int cht = 0; cht < 2; ++cht) {
            int wi = (kn*16 + wv*2 + cht)*64 + lane;
            nah[cht] = wh[wi];
            nal[cht] = wl[wi];
        }
        h8 bh[4], bl[4];
#pragma unroll
        for (int st = 0; st < 4; ++st) {
            int bi = (kg*4 + st)*64 + lane;        // ds_read_b128, conflict-free
            bh[st] = bhp[bi];
            bl[st] = blp[bi];
        }
#pragma unroll
        for (int cht = 0; cht < 2; ++cht)
#pragma unroll
            for (int st = 0; st < 4; ++st)
                acc[cht][st] = mfma3(cah[cht], cal[cht], bh[st], bl[st], acc[cht][st]);
        cah[0] = nah[0]; cah[1] = nah[1];
        cal[0] = nal[0]; cal[1] = nal[1];
    }

    __syncthreads();   // all waves done reading before in-place overwrite

    // relu + hi/lo split into next layer's B-frag layout.
    // ch = wv*32 + cht*16 + q*4 + r  ->  k' bits: kg'=wv, ln'hi=cht*2+(q>>1),
    // j' = (q&1)*4 + r  ->  one ds_write_b64 per (cht,st) per array.
#pragma unroll
    for (int cht = 0; cht < 2; ++cht) {
        int lnp = jl + 16*(cht*2 + (q >> 1));
        int jb  = (q & 1)*4;
#pragma unroll
        for (int st = 0; st < 4; ++st) {
            h4 vh, vl;
#pragma unroll
            for (int r = 0; r < 4; ++r) {
                float v = fmaxf(acc[cht][st][r], 0.0f);
                _Float16 hh = (_Float16)v;
                vh[r] = hh;
                vl[r] = (_Float16)(v - (float)hh);
            }
            int base = ((wv*4 + st)*64 + lnp)*8 + jb;
            *(h4*)(Bhi + base) = vh;
            *(h4*)(Blo + base) = vl;
        }
    }
    __syncthreads();
}

// (512,2): 2nd arg = min BLOCKS/CU on hipcc (r4 evidence: (512,4) -> 64-VGPR
// cap -> scratch spill disaster). 128-VGPR cap matches the 64KB-LDS 2-block limit.
__launch_bounds__(512, 2)
__global__ void nerf_fused(const float* __restrict__ origins,
                           const float* __restrict__ dirs,
                           const float* __restrict__ nearp,
                           const float* __restrict__ farp,
                           const float* __restrict__ b0,
                           const float* __restrict__ b1,
                           const float* __restrict__ b2,
                           const float* __restrict__ b3,
                           const _Float16* __restrict__ ws,
                           float* __restrict__ out)
{
    extern __shared__ _Float16 sm[];
    _Float16* Bhi = sm;            // [kg][4st][64ln][8] = 16384 halfs = 32 KB
    _Float16* Blo = sm + 16384;    // 32 KB (total 64 KB -> 2 blocks/CU, 16 waves)

    const int tid  = threadIdx.x;
    const int wv   = tid >> 6;
    const int lane = tid & 63;
    const int ray  = blockIdx.x;

    const float near = nearp[0];
    const float far  = farp[0];
    const float step = (far - near) * (1.0f / 64.0f);

    const float ox = origins[ray*3+0], oy = origins[ray*3+1], oz = origins[ray*3+2];
    const float dx = dirs[ray*3+0],    dy = dirs[ray*3+1],    dz = dirs[ray*3+2];

    // ---- PE directly into B-frag layout (K padded 63->64): one h8 per thread
    {
        int b  = tid;                    // = (kg*4+st)*64 + ln
        int ln = b & 63;
        int sample = ((b >> 6) & 3)*16 + (ln & 15);
        int k0 = (b >> 8)*32 + ((ln >> 4) << 3);
        float mid = (near + (float)sample*step) + (near + (float)(sample+1)*step)*0.5f;
        float c3[3] = { ox + mid*dx, oy + mid*dy, oz + mid*dz };
        h8 vh, vl;
#pragma unroll
        for (int j = 0; j < 8; ++j) {
            int k = k0 + j;
            float v;
            if (k < 3) v = c3[k];
            else if (k < 63) {
                int t = k - 3, l = t/6, r = t%6, d = r%3;
                float a = c3[d] * (float)(1 << l);
                v = (r < 3) ? sinf(a) : cosf(a);
            } else v = 0.0f;
            _Float16 hh = (_Float16)v;
            vh[j] = hh;
            vl[j] = (_Float16)(v - (float)hh);
        }
        ((h8*)Bhi)[b] = vh;
        ((h8*)Blo)[b] = vl;
    }
    __syncthreads();

    dense_layer<2>(ws+OFF_W0HI, ws+OFF_W0LO, b0, Bhi, Blo, wv, lane);
    dense_layer<8>(ws+OFF_W1HI, ws+OFF_W1LO, b1, Bhi, Blo, wv, lane);
    dense_layer<8>(ws+OFF_W2HI, ws+OFF_W2LO, b2, Bhi, Blo, wv, lane);

    // ---- head: D[16pad ch][64 samp], K split across 8 waves (kg = wv)
    f4 hacc[4];
#pragma unroll
    for (int st = 0; st < 4; ++st) hacc[st] = (f4){0.f, 0.f, 0.f, 0.f};
    {
        h8 ah = ((const h8*)(ws+OFF_W3HI))[wv*64 + lane];
        h8 al = ((const h8*)(ws+OFF_W3LO))[wv*64 + lane];
        const h8* bhp = (const h8*)Bhi;
        const h8* blp = (const h8*)Blo;
#pragma unroll
        for (int st = 0; st < 4; ++st) {
            int bi = (wv*4 + st)*64 + lane;
            hacc[st] = mfma3(ah, al, bhp[bi], blp[bi], hacc[st]);
        }
    }
    __syncthreads();                       // B reads done -> safe to alias

    f4* part = (f4*)sm;                    // [wv][st][lane] f4 = 32 KB (Bhi region)
#pragma unroll
    for (int st = 0; st < 4; ++st) part[(wv*4 + st)*64 + lane] = hacc[st];
    __syncthreads();

    float* headv = (float*)(sm + 16384);   // [64 samp][4] f32 = 1 KB (Blo region)
    if (tid < 256) {
        int st = tid >> 6, l = tid & 63;
        f4 s = part[(0*4 + st)*64 + l];
#pragma unroll
        for (int w = 1; w < 8; ++w) s += part[(w*4 + st)*64 + l];
        int q = l >> 4, jl = l & 15;
        if (q == 0) {                      // rows 0..3 = the real 4 channels
            s += *(const f4*)b3;
            ((f4*)headv)[st*16 + jl] = s;  // [sample] -> (r,g,b,sigma)
        }
    }
    __syncthreads();

    // ---- compositing: wave 0, lane = sample
    if (tid < 64) {
        f4 f = ((const f4*)headv)[tid];
        const int p = tid;
        float sigma = fmaxf(f[3], 0.0f);
        float delta = (near + (float)(p + 1)*step) - (near + (float)p*step);
        float alpha = 1.0f - expf(-sigma * delta);
        float om    = 1.0f - alpha;

        float prod = om;
#pragma unroll
        for (int off = 1; off < 64; off <<= 1) {
            float v = __shfl_up(prod, off, 64);
            if (p >= off) prod *= v;
        }
        float T = __shfl_up(prod, 1, 64);
        if (p == 0) T = 1.0f;
        float w = T * alpha;

        float r  = w * (1.0f / (1.0f + expf(-f[0])));
        float g  = w * (1.0f / (1.0f + expf(-f[1])));
        float bb = w * (1.0f / (1.0f + expf(-f[2])));
#pragma unroll
        for (int off = 32; off > 0; off >>= 1) {
            r  += __shfl_down(r,  off, 64);
            g  += __shfl_down(g,  off, 64);
            bb += __shfl_down(bb, off, 64);
        }
        if (p == 0) {
            out[ray*3 + 0] = r;
            out[ray*3 + 1] = g;
            out[ray*3 + 2] = bb;
        }
    }
}

extern "C" void kernel_launch(void* const* d_in, const int* in_sizes, int n_in,
                              void* d_out, int out_size, void* d_ws, size_t ws_size,
                              hipStream_t stream) {
    const float* origins = (const float*)d_in[0];
    const float* dirs    = (const float*)d_in[1];
    const float* nearp   = (const float*)d_in[2];
    const float* farp    = (const float*)d_in[3];
    const float* W0      = (const float*)d_in[4];
    const float* b0      = (const float*)d_in[5];
    const float* W1      = (const float*)d_in[6];
    const float* b1      = (const float*)d_in[7];
    const float* W2      = (const float*)d_in[8];
    const float* b2      = (const float*)d_in[9];
    const float* W3      = (const float*)d_in[10];
    const float* b3      = (const float*)d_in[11];
    float* out           = (float*)d_out;
    _Float16* ws         = (_Float16*)d_ws;

    const int nrays = in_sizes[0] / 3;

    prep_weights<<<dim3(74), dim3(256), 0, stream>>>(W0, W1, W2, W3, ws);

    const size_t shmem = 32768 * sizeof(_Float16);   // 64 KiB
    hipFuncSetAttribute(reinterpret_cast<const void*>(nerf_fused),
                        hipFuncAttributeMaxDynamicSharedMemorySize,
                        (int)shmem);
    nerf_fused<<<dim3(nrays), dim3(512), shmem, stream>>>(
        origins, dirs, nearp, farp, b0, b1, b2, b3, ws, out);
}